// Round 10
// baseline (718.865 us; speedup 1.0000x reference)
//
#include <hip/hip_runtime.h>

// MixerBlock: B=8, T=2048, E=1024, H=16, HD=64, DFF=4096, DC=4
// r10: real pipeline = round-6 config (best, 531 us) UNCHANGED.
// Plus 2 ablation decoys on G4's shape (write to dead wP scratch):
//   ablA_nostage  nt=64  : no gload/vmcnt; LDS zeroed; ds_read+MFMA+barriers.
//   ablB_nomfma   nt=128 : full staging machine, MFMA removed (asm sinks).
// Purpose: decompose the invariant ~6700 cyc/tile into memory vs compute vs
// barrier components (7 schedule/tile/locality variants were all null).

#define TT 2048
#define EE 1024
#define HHD 64
#define MROWS 16384
#define SC_L 64

typedef __bf16 bf16x8 __attribute__((ext_vector_type(8)));
typedef float f32x4 __attribute__((ext_vector_type(4)));
typedef unsigned short u16;
typedef unsigned int u32;

__device__ __forceinline__ u16 f2bf(float f) {
  u32 u = __builtin_bit_cast(u32, f);
  u += 0x7FFFu + ((u >> 16) & 1u);      // round-to-nearest-even
  return (u16)(u >> 16);
}
__device__ __forceinline__ float bf2f(u16 s) {
  u32 u = ((u32)s) << 16;
  return __builtin_bit_cast(float, u);
}
__device__ __forceinline__ float gelu_f(float x) {
  float x2 = x * x;
  float e = -1.5957691216057308f * x * __builtin_fmaf(0.044715f, x2, 1.0f);
  return x * __builtin_amdgcn_rcpf(1.0f + __expf(e));
}
__device__ __forceinline__ void gload_lds16(const void* g, void* l) {
  __builtin_amdgcn_global_load_lds(
      (const __attribute__((address_space(1))) u32*)g,
      (__attribute__((address_space(3))) u32*)l, 16, 0, 0);
}
__device__ __forceinline__ void wg_barrier() {
  asm volatile("" ::: "memory");
  __builtin_amdgcn_s_barrier();
  asm volatile("" ::: "memory");
}

// ---------------- weight transpose + cast
__global__ __launch_bounds__(256) void transpose_to_bf16(
    const float* __restrict__ src, u16* __restrict__ dst, int R, int C,
    long sbs, long dbs) {
  __shared__ float tile[32][33];
  src += (long)blockIdx.z * sbs;
  dst += (long)blockIdx.z * dbs;
  int c0 = blockIdx.x * 32, r0 = blockIdx.y * 32;
  int tx = threadIdx.x, ty = threadIdx.y;
#pragma unroll
  for (int i = 0; i < 4; i++)
    tile[ty + i * 8][tx] = src[(long)(r0 + ty + i * 8) * C + c0 + tx];
  __syncthreads();
#pragma unroll
  for (int i = 0; i < 4; i++)
    dst[(long)(c0 + ty + i * 8) * R + r0 + tx] = f2bf(tile[tx][ty + i * 8]);
}

// ---------------- LayerNorm over E=1024
__global__ __launch_bounds__(256) void ln_to_bf16(
    const float* __restrict__ x, const float* __restrict__ gam,
    const float* __restrict__ bet, u16* __restrict__ y) {
  int row = blockIdx.x;
  int tid = threadIdx.x;
  float4 v = ((const float4*)x)[row * 256 + tid];
  float s = v.x + v.y + v.z + v.w;
  float s2 = v.x * v.x + v.y * v.y + v.z * v.z + v.w * v.w;
#pragma unroll
  for (int off = 1; off < 64; off <<= 1) {
    s += __shfl_xor(s, off);
    s2 += __shfl_xor(s2, off);
  }
  __shared__ float red[8];
  int w = tid >> 6;
  if ((tid & 63) == 0) { red[w] = s; red[4 + w] = s2; }
  __syncthreads();
  s = red[0] + red[1] + red[2] + red[3];
  s2 = red[4] + red[5] + red[6] + red[7];
  float mu = s * (1.0f / 1024.0f);
  float var = s2 * (1.0f / 1024.0f) - mu * mu;
  float rstd = rsqrtf(var + 1e-5f);
  int e0 = tid * 4;
  ushort4 o;
  o.x = f2bf((v.x - mu) * rstd * gam[e0 + 0] + bet[e0 + 0]);
  o.y = f2bf((v.y - mu) * rstd * gam[e0 + 1] + bet[e0 + 1]);
  o.z = f2bf((v.z - mu) * rstd * gam[e0 + 2] + bet[e0 + 2]);
  o.w = f2bf((v.w - mu) * rstd * gam[e0 + 3] + bet[e0 + 3]);
  ((ushort4*)y)[row * 256 + tid] = o;
}

// ---------------- bf16 GEMM, 256x256, BK=64, deep-staggered counted-vmcnt
// (round-6 config, verbatim). A: (M x K) rm. Bt: (N x K) rm.
template <int EPI>
__global__ __launch_bounds__(512, 2) void gemm256(
    const u16* __restrict__ A, const u16* __restrict__ Bt,
    const float* __restrict__ bias, const float* __restrict__ res, void* outp,
    int M, int N, int K, int px, int gxp, int byper) {
  __shared__ u16 lds[65536];
  const int tid = threadIdx.x;
  const int w = tid >> 6, lane = tid & 63;
  const int wm = w >> 2, wn = w & 3;
  const int l15 = lane & 15, lk = lane >> 4;

  const int gx = (int)gridDim.x;
  const int bid = (int)blockIdx.y * gx + (int)blockIdx.x;
  const int xcd = bid & 7, i = bid >> 3;
  const int xg = xcd % gxp, yg = xcd / gxp;
  const int bx = xg * px + (i % px);
  const int by = yg * byper + (i / px);
  const int m0 = by * 256, n0 = bx * 256;

  const int srow = w * 8 + (lane >> 3);
  const int sslot = (lane & 7) ^ (lane >> 3);
  const u16* aS = A + (size_t)(m0 + srow) * K + sslot * 8;
  const u16* bS = Bt + (size_t)(n0 + srow) * K + sslot * 8;

  f32x4 acc[8][4];
  const f32x4 z = {0.f, 0.f, 0.f, 0.f};
#pragma unroll
  for (int mi = 0; mi < 8; mi++)
#pragma unroll
    for (int ni = 0; ni < 4; ni++) acc[mi][ni] = z;

  bf16x8 a[4], b0[4], b1[4];

#define STAGE_B(C, KT, H) { \
    u16* lb = lds + (C) * 32768 + 16384 + (H) * 8192 + w * 512; \
    gload_lds16(bS + (size_t)((H) * 128) * K + (KT), lb); \
    gload_lds16(bS + (size_t)((H) * 128 + 64) * K + (KT), lb + 4096); }
#define STAGE_A02(C, KT) { \
    u16* lb = lds + (C) * 32768 + w * 512; \
    gload_lds16(aS + (KT), lb); \
    gload_lds16(aS + (size_t)128 * K + (KT), lb + 8192); }
#define STAGE_A13(C, KT) { \
    u16* lb = lds + (C) * 32768 + 4096 + w * 512; \
    gload_lds16(aS + (size_t)64 * K + (KT), lb); \
    gload_lds16(aS + (size_t)192 * K + (KT), lb + 8192); }
#define RD_A(C, KS, MH) { \
    const bf16x8* lp = (const bf16x8*)(lds + (C) * 32768); \
    const int sl = ((KS) * 4 + lk) ^ (l15 & 7); \
    const int rb = wm * 128 + (MH) * 64 + l15; \
    a[0] = lp[rb * 8 + sl]; \
    a[1] = lp[(rb + 16) * 8 + sl]; \
    a[2] = lp[(rb + 32) * 8 + sl]; \
    a[3] = lp[(rb + 48) * 8 + sl]; }
#define RD_B(BV, C, KS) { \
    const bf16x8* lp = (const bf16x8*)(lds + (C) * 32768 + 16384); \
    const int sl = ((KS) * 4 + lk) ^ (l15 & 7); \
    const int rb = wn * 64 + l15; \
    BV[0] = lp[rb * 8 + sl]; \
    BV[1] = lp[(rb + 16) * 8 + sl]; \
    BV[2] = lp[(rb + 32) * 8 + sl]; \
    BV[3] = lp[(rb + 48) * 8 + sl]; }
#define MFMA16(MH, BV) { \
    __builtin_amdgcn_s_setprio(1); \
    _Pragma("unroll") \
    for (int mm = 0; mm < 4; mm++) \
      _Pragma("unroll") \
      for (int nn = 0; nn < 4; nn++) \
        acc[(MH) * 4 + mm][nn] = __builtin_amdgcn_mfma_f32_16x16x32_bf16( \
            a[mm], BV[nn], acc[(MH) * 4 + mm][nn], 0, 0, 0); \
    __builtin_amdgcn_s_setprio(0); }

  const int nt = K >> 6;
  STAGE_B(0, 0, 0);
  STAGE_B(0, 0, 1);
  STAGE_A02(0, 0);
  STAGE_A13(0, 0);
  asm volatile("s_waitcnt vmcnt(0)" ::: "memory");
  wg_barrier();

  int cur = 0;
  for (int t = 0; t < nt - 1; ++t) {
    const int kn = (t + 1) << 6;
    const int nx = cur ^ 1;
    RD_B(b0, cur, 0);
    RD_A(cur, 0, 0);
    STAGE_B(nx, kn, 0);
    STAGE_B(nx, kn, 1);
    STAGE_A02(nx, kn);
    wg_barrier();
    MFMA16(0, b0);
    wg_barrier();
    RD_B(b1, cur, 1);
    RD_A(cur, 1, 0);
    STAGE_A13(nx, kn);
    wg_barrier();
    MFMA16(0, b1);
    asm volatile("s_waitcnt vmcnt(8)" ::: "memory");
    wg_barrier();
    RD_A(cur, 0, 1);
    wg_barrier();
    MFMA16(1, b0);
    wg_barrier();
    RD_A(cur, 1, 1);
    wg_barrier();
    MFMA16(1, b1);
    asm volatile("s_waitcnt vmcnt(2)" ::: "memory");
    wg_barrier();
    cur = nx;
  }
  RD_B(b0, cur, 0);
  RD_A(cur, 0, 0);
  MFMA16(0, b0);
  RD_B(b1, cur, 1);
  RD_A(cur, 1, 0);
  MFMA16(0, b1);
  asm volatile("s_waitcnt vmcnt(0)" ::: "memory");
  wg_barrier();
  RD_A(cur, 0, 1);
  MFMA16(1, b0);
  RD_A(cur, 1, 1);
  MFMA16(1, b1);
#undef STAGE_B
#undef STAGE_A02
#undef STAGE_A13
#undef RD_A
#undef RD_B
#undef MFMA16

#pragma unroll
  for (int mi = 0; mi < 8; mi++) {
#pragma unroll
    for (int ni = 0; ni < 4; ni++) {
      int n = n0 + wn * 64 + ni * 16 + l15;
      float bvv = bias[n];
#pragma unroll
      for (int r = 0; r < 4; r++) {
        int m = m0 + wm * 128 + mi * 16 + lk * 4 + r;
        size_t idx = (size_t)m * N + n;
        float v = acc[mi][ni][r] + bvv;
        if (EPI == 0) {
          ((u16*)outp)[idx] = f2bf(v);
        } else if (EPI == 1) {
          ((float*)outp)[idx] = v + res[idx];
        } else {
          ((u16*)outp)[idx] = f2bf(gelu_f(v));
        }
      }
    }
  }
}

// ---------------- ABLATION decoys: same structure, MODE 1 = nostage
// (no gload/vmcnt, LDS zeroed), MODE 2 = nomfma (frags sunk via asm).
// ntov = tile count (kt wraps mod real K). Output to dead scratch as bf16.
template <int MODE>
__global__ __launch_bounds__(512, 2) void abl_gemm(
    const u16* __restrict__ A, const u16* __restrict__ Bt, u16* __restrict__ outp,
    int M, int N, int K, int px, int gxp, int byper, int ntov) {
  __shared__ u16 lds[65536];
  const int tid = threadIdx.x;
  const int w = tid >> 6, lane = tid & 63;
  const int wm = w >> 2, wn = w & 3;
  const int l15 = lane & 15, lk = lane >> 4;

  const int gx = (int)gridDim.x;
  const int bid = (int)blockIdx.y * gx + (int)blockIdx.x;
  const int xcd = bid & 7, i = bid >> 3;
  const int bx = (xcd % gxp) * px + (i % px);
  const int by = (xcd / gxp) * byper + (i / px);
  const int m0 = by * 256, n0 = bx * 256;

  const int srow = w * 8 + (lane >> 3);
  const int sslot = (lane & 7) ^ (lane >> 3);
  const u16* aS = A + (size_t)(m0 + srow) * K + sslot * 8;
  const u16* bS = Bt + (size_t)(n0 + srow) * K + sslot * 8;

  f32x4 acc[8][4];
  const f32x4 z = {0.f, 0.f, 0.f, 0.f};
#pragma unroll
  for (int mi = 0; mi < 8; mi++)
#pragma unroll
    for (int ni = 0; ni < 4; ni++) acc[mi][ni] = z;

  bf16x8 a[4], b0[4], b1[4];

  if (MODE == 1) {  // zero LDS once so ds_reads are defined; no vm ops at all
    for (int k = tid * 8; k < 65536; k += 512 * 8)
      *(bf16x8*)(lds + k) = bf16x8{};
    wg_barrier();
  }

#define ASTAGE_B(C, KT, H) if (MODE != 1) { \
    u16* lb = lds + (C) * 32768 + 16384 + (H) * 8192 + w * 512; \
    gload_lds16(bS + (size_t)((H) * 128) * K + (KT), lb); \
    gload_lds16(bS + (size_t)((H) * 128 + 64) * K + (KT), lb + 4096); }
#define ASTAGE_A02(C, KT) if (MODE != 1) { \
    u16* lb = lds + (C) * 32768 + w * 512; \
    gload_lds16(aS + (KT), lb); \
    gload_lds16(aS + (size_t)128 * K + (KT), lb + 8192); }
#define ASTAGE_A13(C, KT) if (MODE != 1) { \
    u16* lb = lds + (C) * 32768 + 4096 + w * 512; \
    gload_lds16(aS + (size_t)64 * K + (KT), lb); \
    gload_lds16(aS + (size_t)192 * K + (KT), lb + 8192); }
#define ARD_A(C, KS, MH) { \
    const bf16x8* lp = (const bf16x8*)(lds + (C) * 32768); \
    const int sl = ((KS) * 4 + lk) ^ (l15 & 7); \
    const int rb = wm * 128 + (MH) * 64 + l15; \
    a[0] = lp[rb * 8 + sl]; \
    a[1] = lp[(rb + 16) * 8 + sl]; \
    a[2] = lp[(rb + 32) * 8 + sl]; \
    a[3] = lp[(rb + 48) * 8 + sl]; \
    if (MODE == 2) asm volatile("" :: "v"(a[0]), "v"(a[1]), "v"(a[2]), "v"(a[3])); }
#define ARD_B(BV, C, KS) { \
    const bf16x8* lp = (const bf16x8*)(lds + (C) * 32768 + 16384); \
    const int sl = ((KS) * 4 + lk) ^ (l15 & 7); \
    const int rb = wn * 64 + l15; \
    BV[0] = lp[rb * 8 + sl]; \
    BV[1] = lp[(rb + 16) * 8 + sl]; \
    BV[2] = lp[(rb + 32) * 8 + sl]; \
    BV[3] = lp[(rb + 48) * 8 + sl]; \
    if (MODE == 2) asm volatile("" :: "v"(BV[0]), "v"(BV[1]), "v"(BV[2]), "v"(BV[3])); }
#define AMFMA16(MH, BV) if (MODE != 2) { \
    __builtin_amdgcn_s_setprio(1); \
    _Pragma("unroll") \
    for (int mm = 0; mm < 4; mm++) \
      _Pragma("unroll") \
      for (int nn = 0; nn < 4; nn++) \
        acc[(MH) * 4 + mm][nn] = __builtin_amdgcn_mfma_f32_16x16x32_bf16( \
            a[mm], BV[nn], acc[(MH) * 4 + mm][nn], 0, 0, 0); \
    __builtin_amdgcn_s_setprio(0); }
#define AVM(N_) if (MODE != 1) { asm volatile("s_waitcnt vmcnt(" #N_ ")" ::: "memory"); }

  ASTAGE_B(0, 0, 0);
  ASTAGE_B(0, 0, 1);
  ASTAGE_A02(0, 0);
  ASTAGE_A13(0, 0);
  AVM(0);
  wg_barrier();

  const int ktmask = (K >> 6) - 1;
  int cur = 0;
  for (int t = 0; t < ntov - 1; ++t) {
    const int kn = (((t + 1) & ktmask)) << 6;
    const int nx = cur ^ 1;
    ARD_B(b0, cur, 0);
    ARD_A(cur, 0, 0);
    ASTAGE_B(nx, kn, 0);
    ASTAGE_B(nx, kn, 1);
    ASTAGE_A02(nx, kn);
    wg_barrier();
    AMFMA16(0, b0);
    wg_barrier();
    ARD_B(b1, cur, 1);
    ARD_A(cur, 1, 0);
    ASTAGE_A13(nx, kn);
    wg_barrier();
    AMFMA16(0, b1);
    AVM(8);
    wg_barrier();
    ARD_A(cur, 0, 1);
    wg_barrier();
    AMFMA16(1, b0);
    wg_barrier();
    ARD_A(cur, 1, 1);
    wg_barrier();
    AMFMA16(1, b1);
    AVM(2);
    wg_barrier();
    cur = nx;
  }
  ARD_B(b0, cur, 0);
  ARD_A(cur, 0, 0);
  AMFMA16(0, b0);
  ARD_B(b1, cur, 1);
  ARD_A(cur, 1, 0);
  AMFMA16(0, b1);
  AVM(0);
  wg_barrier();
  ARD_A(cur, 0, 1);
  AMFMA16(1, b0);
  ARD_A(cur, 1, 1);
  AMFMA16(1, b1);
#undef ASTAGE_B
#undef ASTAGE_A02
#undef ASTAGE_A13
#undef ARD_A
#undef ARD_B
#undef AMFMA16
#undef AVM

#pragma unroll
  for (int mi = 0; mi < 8; mi++) {
#pragma unroll
    for (int ni = 0; ni < 4; ni++) {
      int n = n0 + wn * 64 + ni * 16 + l15;
#pragma unroll
      for (int r = 0; r < 4; r++) {
        int m = m0 + wm * 128 + mi * 16 + lk * 4 + r;
        outp[(size_t)m * N + n] = f2bf(acc[mi][ni][r]);
      }
    }
  }
}

// ---------------- causal decay scan
__global__ __launch_bounds__(64) void scan_carry(
    const u16* __restrict__ p, const float* __restrict__ mix_w,
    const float* __restrict__ decay, float* __restrict__ carry) {
  int blk = blockIdx.x;
  int c = blk & 31, h = (blk >> 5) & 15, b = blk >> 9;
  int f = threadIdx.x;
  float d = fminf(fmaxf(decay[h], 0.9f), 1.0f);
  float r = powf(d, 0.25f);
  size_t base = ((size_t)b * TT + c * SC_L) * EE + h * HHD + f;
  const float* mw = mix_w + h * TT + c * SC_L;
  bool isRow = (h >= 8);
  float S = 0.f;
#pragma unroll 4
  for (int t = 0; t < SC_L; t++) {
    float pv = bf2f(p[base + (size_t)t * EE]);
    float q = isRow ? mw[t] * pv : pv;
    S = r * S + q;
  }
  carry[blk * 64 + f] = S;
}

__global__ __launch_bounds__(64) void scan_apply(
    const u16* __restrict__ p, const float* __restrict__ mix_w,
    const float* __restrict__ mix_b, const float* __restrict__ decay,
    const float* __restrict__ carry, u16* __restrict__ mixed) {
  int blk = blockIdx.x;
  int c = blk & 31, h = (blk >> 5) & 15, b = blk >> 9;
  int f = threadIdx.x;
  float d = fminf(fmaxf(decay[h], 0.9f), 1.0f);
  float r = powf(d, 0.25f);
  float rl = powf(r, (float)SC_L);
  int cb = blk - c;
  float S = 0.f;
  for (int cc = 0; cc < c; cc++) S = rl * S + carry[(cb + cc) * 64 + f];
  size_t base = ((size_t)b * TT + c * SC_L) * EE + h * HHD + f;
  const float* mw = mix_w + h * TT + c * SC_L;
  const float* mb = mix_b + h * TT + c * SC_L;
  bool isRow = (h >= 8);
  for (int t = 0; t < SC_L; t++) {
    float pv = bf2f(p[base + (size_t)t * EE]);
    float q = isRow ? mw[t] * pv : pv;
    S = r * S + q;
    float val = (isRow ? S : mw[t] * S) + mb[t];
    mixed[base + (size_t)t * EE] = f2bf(val);
  }
}

extern "C" void kernel_launch(void* const* d_in, const int* in_sizes, int n_in,
                              void* d_out, int out_size, void* d_ws, size_t ws_size,
                              hipStream_t stream) {
  const float* x = (const float*)d_in[0];
  const float* w_proj = (const float*)d_in[1];
  const float* b_proj = (const float*)d_in[2];
  const float* mix_w = (const float*)d_in[3];
  const float* mix_b = (const float*)d_in[4];
  const float* decay = (const float*)d_in[5];
  const float* out_w = (const float*)d_in[6];
  const float* out_b = (const float*)d_in[7];
  const float* ln1_g = (const float*)d_in[8];
  const float* ln1_b = (const float*)d_in[9];
  const float* ln2_g = (const float*)d_in[10];
  const float* ln2_b = (const float*)d_in[11];
  const float* ff_w1 = (const float*)d_in[12];
  const float* ff_b1 = (const float*)d_in[13];
  const float* ff_w2 = (const float*)d_in[14];
  const float* ff_b2 = (const float*)d_in[15];
  float* out = (float*)d_out;

  char* ws = (char*)d_ws;
  const size_t MiB = 1ull << 20;
  u16* wWp = (u16*)(ws + 0 * MiB);
  u16* wWo = (u16*)(ws + 2 * MiB);
  u16* wW1 = (u16*)(ws + 4 * MiB);
  u16* wW2 = (u16*)(ws + 12 * MiB);
  u16* wMix = (u16*)(ws + 20 * MiB);
  u16* wH = (u16*)(ws + 52 * MiB);
  u16* wP = (u16*)(ws + 84 * MiB);
  u16* wU = (u16*)(ws + 52 * MiB);
  float* wCarry = (float*)(ws + 180 * MiB);

  dim3 tb(32, 8);
  transpose_to_bf16<<<dim3(2, 32, 16), tb, 0, stream>>>(w_proj, wWp, 1024, 64,
                                                        65536L, 65536L);
  transpose_to_bf16<<<dim3(32, 32, 1), tb, 0, stream>>>(out_w, wWo, 1024, 1024, 0L, 0L);
  transpose_to_bf16<<<dim3(128, 32, 1), tb, 0, stream>>>(ff_w1, wW1, 1024, 4096, 0L, 0L);
  transpose_to_bf16<<<dim3(32, 128, 1), tb, 0, stream>>>(ff_w2, wW2, 4096, 1024, 0L, 0L);

  ln_to_bf16<<<dim3(MROWS), dim3(256), 0, stream>>>(x, ln1_g, ln1_b, wH);

  gemm256<0><<<dim3(4, 64), dim3(512), 0, stream>>>(
      wH, wWp, b_proj, (const float*)nullptr, (void*)wP, MROWS, 1024, 1024,
      4, 1, 8);

  scan_carry<<<dim3(4096), dim3(64), 0, stream>>>(wP, mix_w, decay, wCarry);
  scan_apply<<<dim3(4096), dim3(64), 0, stream>>>(wP, mix_w, mix_b, decay, wCarry, wMix);

  gemm256<1><<<dim3(4, 64), dim3(512), 0, stream>>>(
      wMix, wWo, out_b, x, (void*)out, MROWS, 1024, 1024,
      4, 1, 8);

  ln_to_bf16<<<dim3(MROWS), dim3(256), 0, stream>>>(out, ln2_g, ln2_b, wMix);

  gemm256<2><<<dim3(16, 64), dim3(512), 0, stream>>>(
      wMix, wW1, ff_b1, (const float*)nullptr, (void*)wU, MROWS, 4096, 1024,
      4, 4, 32);

  gemm256<1><<<dim3(4, 64), dim3(512), 0, stream>>>(
      wU, wW2, ff_b2, out, (void*)out, MROWS, 1024, 4096,
      2, 2, 16);

  // ---- ablation decoys (write to dead wP scratch; G4 shape) ----
  abl_gemm<1><<<dim3(4, 64), dim3(512), 0, stream>>>(
      wU, wW2, wP, MROWS, 1024, 4096, 2, 2, 16, 64);    // ablA_nostage, nt=64
  abl_gemm<2><<<dim3(4, 64), dim3(512), 0, stream>>>(
      wU, wW2, wP, MROWS, 1024, 4096, 2, 2, 16, 128);   // ablB_nomfma, nt=128
}

// Round 11
// 698.311 us; speedup vs baseline: 1.0294x; 1.0294x over previous
//
#include <hip/hip_runtime.h>

// MixerBlock: B=8, T=2048, E=1024, H=16, HD=64, DFF=4096, DC=4
// GEMM r11: PRODUCER-CONSUMER wave specialization. 256x256 tile, BK=64,
// 9 waves (576 thr): waves 0-7 = consumers (2Mx4N, 128x64 out each), wave 8 =
// producer. Per tile: producer issues 64 global_load_lds for t+1 -> buf nx,
// then vmcnt(0) IN ITS OWN WAVE (overlaps consumer compute), then the single
// per-tile s_barrier. Consumers: free-run reads+MFMA from buf cur (no vmcnt,
// no staging), then the same barrier. One barrier per tile.
// Race ledger: producer vmcnt(0) precedes barrier => t+1 resident at barrier;
// consumers' reads of cur precede barrier => producer overwrites cur only
// after it (next iteration). Barrier counts identical in both roles.
// LDS layout (proven 0-conflict): per matrix [256 rows][8 slots of 8 bf16],
// LDS slot s holds global slot s^(row&7) via pre-swizzled source (rule #21);
// read slot = (ks*4+lk)^(l15&7). Supertile XCD swizzle as r6.

#define TT 2048
#define EE 1024
#define HHD 64
#define MROWS 16384
#define SC_L 64

typedef __bf16 bf16x8 __attribute__((ext_vector_type(8)));
typedef float f32x4 __attribute__((ext_vector_type(4)));
typedef unsigned short u16;
typedef unsigned int u32;

__device__ __forceinline__ u16 f2bf(float f) {
  u32 u = __builtin_bit_cast(u32, f);
  u += 0x7FFFu + ((u >> 16) & 1u);      // round-to-nearest-even
  return (u16)(u >> 16);
}
__device__ __forceinline__ float bf2f(u16 s) {
  u32 u = ((u32)s) << 16;
  return __builtin_bit_cast(float, u);
}
__device__ __forceinline__ float gelu_f(float x) {
  float x2 = x * x;
  float e = -1.5957691216057308f * x * __builtin_fmaf(0.044715f, x2, 1.0f);
  return x * __builtin_amdgcn_rcpf(1.0f + __expf(e));
}
__device__ __forceinline__ void gload_lds16(const void* g, void* l) {
  __builtin_amdgcn_global_load_lds(
      (const __attribute__((address_space(1))) u32*)g,
      (__attribute__((address_space(3))) u32*)l, 16, 0, 0);
}
__device__ __forceinline__ void wg_barrier() {
  asm volatile("" ::: "memory");
  __builtin_amdgcn_s_barrier();
  asm volatile("" ::: "memory");
}

// ---------------- weight transpose + cast
__global__ __launch_bounds__(256) void transpose_to_bf16(
    const float* __restrict__ src, u16* __restrict__ dst, int R, int C,
    long sbs, long dbs) {
  __shared__ float tile[32][33];
  src += (long)blockIdx.z * sbs;
  dst += (long)blockIdx.z * dbs;
  int c0 = blockIdx.x * 32, r0 = blockIdx.y * 32;
  int tx = threadIdx.x, ty = threadIdx.y;
#pragma unroll
  for (int i = 0; i < 4; i++)
    tile[ty + i * 8][tx] = src[(long)(r0 + ty + i * 8) * C + c0 + tx];
  __syncthreads();
#pragma unroll
  for (int i = 0; i < 4; i++)
    dst[(long)(c0 + ty + i * 8) * R + r0 + tx] = f2bf(tile[tx][ty + i * 8]);
}

// ---------------- LayerNorm over E=1024
__global__ __launch_bounds__(256) void ln_to_bf16(
    const float* __restrict__ x, const float* __restrict__ gam,
    const float* __restrict__ bet, u16* __restrict__ y) {
  int row = blockIdx.x;
  int tid = threadIdx.x;
  float4 v = ((const float4*)x)[row * 256 + tid];
  float s = v.x + v.y + v.z + v.w;
  float s2 = v.x * v.x + v.y * v.y + v.z * v.z + v.w * v.w;
#pragma unroll
  for (int off = 1; off < 64; off <<= 1) {
    s += __shfl_xor(s, off);
    s2 += __shfl_xor(s2, off);
  }
  __shared__ float red[8];
  int w = tid >> 6;
  if ((tid & 63) == 0) { red[w] = s; red[4 + w] = s2; }
  __syncthreads();
  s = red[0] + red[1] + red[2] + red[3];
  s2 = red[4] + red[5] + red[6] + red[7];
  float mu = s * (1.0f / 1024.0f);
  float var = s2 * (1.0f / 1024.0f) - mu * mu;
  float rstd = rsqrtf(var + 1e-5f);
  int e0 = tid * 4;
  ushort4 o;
  o.x = f2bf((v.x - mu) * rstd * gam[e0 + 0] + bet[e0 + 0]);
  o.y = f2bf((v.y - mu) * rstd * gam[e0 + 1] + bet[e0 + 1]);
  o.z = f2bf((v.z - mu) * rstd * gam[e0 + 2] + bet[e0 + 2]);
  o.w = f2bf((v.w - mu) * rstd * gam[e0 + 3] + bet[e0 + 3]);
  ((ushort4*)y)[row * 256 + tid] = o;
}

// ---------------- bf16 GEMM, 256x256, BK=64, producer-consumer.
// A: (M x K) bf16 rm. Bt: (N x K) bf16 rm.
// LDS buffer c at c*32768 (u16): A [0,16384), B [16384,32768).
// EPI 0: bf16 = acc+bias ; 1: f32 = acc+bias+res ; 2: bf16 = gelu(acc+bias)
template <int EPI>
__global__ __launch_bounds__(576, 1) void gemm256pc(
    const u16* __restrict__ A, const u16* __restrict__ Bt,
    const float* __restrict__ bias, const float* __restrict__ res, void* outp,
    int M, int N, int K, int px, int gxp, int byper) {
  __shared__ u16 lds[65536];  // 128 KiB
  const int tid = threadIdx.x;
  const int w = tid >> 6, lane = tid & 63;

  // T1: L2-locality supertile swizzle (bijective; nwg % 8 == 0 always)
  const int gx = (int)gridDim.x;
  const int bid = (int)blockIdx.y * gx + (int)blockIdx.x;
  const int xcd = bid & 7, i = bid >> 3;
  const int bx = (xcd % gxp) * px + (i % px);
  const int by = (xcd / gxp) * byper + (i / px);
  const int m0 = by * 256, n0 = bx * 256;

  const int nt = K >> 6;

  if (w == 8) {
    // ---------------- PRODUCER wave ----------------
    // chunk c covers rows 8c..8c+7; lane L -> row 8c+(L>>3), slot L&7,
    // global slot pre-swizzled by row&7 = (L>>3). LDS dst = base + L*16B.
    const int rl = lane >> 3;
    const int ssl = ((lane & 7) ^ (lane >> 3)) * 8;
    const u16* aP = A + (size_t)(m0 + rl) * K + ssl;
    const u16* bP = Bt + (size_t)(n0 + rl) * K + ssl;
    const size_t cstride = (size_t)8 * K;

#define PSTAGE(C, KT) { \
    u16* lb = lds + (C) * 32768; \
    _Pragma("unroll 8") \
    for (int c = 0; c < 32; ++c) { \
      gload_lds16(aP + (size_t)c * cstride + (KT), lb + c * 512); \
      gload_lds16(bP + (size_t)c * cstride + (KT), lb + 16384 + c * 512); \
    } }

    PSTAGE(0, 0);
    asm volatile("s_waitcnt vmcnt(0)" ::: "memory");
    wg_barrier();                      // tile 0 resident for everyone
    for (int t = 0; t < nt; ++t) {
      if (t + 1 < nt) {
        PSTAGE((t + 1) & 1, (t + 1) << 6);                // 64 loads for t+1
        asm volatile("s_waitcnt vmcnt(0)" ::: "memory");  // own-wave wait,
      }                                                   // overlaps consumers
      wg_barrier();                    // end of tile t / t+1 ready
    }
#undef PSTAGE
    return;  // producer skips epilogue (no barriers after loop)
  }

  // ---------------- CONSUMER waves (0-7, 2M x 4N) ----------------
  const int wm = w >> 2, wn = w & 3;
  const int l15 = lane & 15, lk = lane >> 4;
  const int sl0 = (lk ^ (l15 & 7)) * 8;        // u16 offset of ks0 slot
  const int sl1 = ((4 + lk) ^ (l15 & 7)) * 8;  // ks1

  f32x4 acc[8][4];
  const f32x4 z = {0.f, 0.f, 0.f, 0.f};
#pragma unroll
  for (int mi = 0; mi < 8; mi++)
#pragma unroll
    for (int ni = 0; ni < 4; ni++) acc[mi][ni] = z;

  wg_barrier();  // matches producer's post-prologue barrier
  for (int t = 0; t < nt; ++t) {
    const int cur = t & 1;
    const u16* lA = lds + cur * 32768;
    const u16* lB = lA + 16384;
    bf16x8 bq0[4], bq1[4];
    {
      const u16* bp = lB + (wn * 64 + l15) * 64;
#pragma unroll
      for (int ni = 0; ni < 4; ni++) {
        bq0[ni] = *(const bf16x8*)(bp + ni * 1024 + sl0);
        bq1[ni] = *(const bf16x8*)(bp + ni * 1024 + sl1);
      }
    }
#pragma unroll
    for (int mi = 0; mi < 8; mi++) {
      const u16* ap = lA + (wm * 128 + mi * 16 + l15) * 64;
      bf16x8 a0 = *(const bf16x8*)(ap + sl0);
      bf16x8 a1 = *(const bf16x8*)(ap + sl1);
      __builtin_amdgcn_s_setprio(1);
#pragma unroll
      for (int ni = 0; ni < 4; ni++)
        acc[mi][ni] = __builtin_amdgcn_mfma_f32_16x16x32_bf16(a0, bq0[ni],
                                                              acc[mi][ni], 0, 0, 0);
#pragma unroll
      for (int ni = 0; ni < 4; ni++)
        acc[mi][ni] = __builtin_amdgcn_mfma_f32_16x16x32_bf16(a1, bq1[ni],
                                                              acc[mi][ni], 0, 0, 0);
      __builtin_amdgcn_s_setprio(0);
    }
    wg_barrier();  // end of tile t (cur free for producer's t+2)
  }

#pragma unroll
  for (int mi = 0; mi < 8; mi++) {
#pragma unroll
    for (int ni = 0; ni < 4; ni++) {
      int n = n0 + wn * 64 + ni * 16 + l15;       // C/D: col = lane&15
      float bvv = bias[n];
#pragma unroll
      for (int r = 0; r < 4; r++) {
        int m = m0 + wm * 128 + mi * 16 + lk * 4 + r;  // row = (lane>>4)*4 + reg
        size_t idx = (size_t)m * N + n;
        float v = acc[mi][ni][r] + bvv;
        if (EPI == 0) {
          ((u16*)outp)[idx] = f2bf(v);
        } else if (EPI == 1) {
          ((float*)outp)[idx] = v + res[idx];
        } else {
          ((u16*)outp)[idx] = f2bf(gelu_f(v));
        }
      }
    }
  }
}

// ---------------- causal decay scan
__global__ __launch_bounds__(64) void scan_carry(
    const u16* __restrict__ p, const float* __restrict__ mix_w,
    const float* __restrict__ decay, float* __restrict__ carry) {
  int blk = blockIdx.x;
  int c = blk & 31, h = (blk >> 5) & 15, b = blk >> 9;
  int f = threadIdx.x;
  float d = fminf(fmaxf(decay[h], 0.9f), 1.0f);
  float r = powf(d, 0.25f);
  size_t base = ((size_t)b * TT + c * SC_L) * EE + h * HHD + f;
  const float* mw = mix_w + h * TT + c * SC_L;
  bool isRow = (h >= 8);
  float S = 0.f;
#pragma unroll 4
  for (int t = 0; t < SC_L; t++) {
    float pv = bf2f(p[base + (size_t)t * EE]);
    float q = isRow ? mw[t] * pv : pv;
    S = r * S + q;
  }
  carry[blk * 64 + f] = S;
}

__global__ __launch_bounds__(64) void scan_apply(
    const u16* __restrict__ p, const float* __restrict__ mix_w,
    const float* __restrict__ mix_b, const float* __restrict__ decay,
    const float* __restrict__ carry, u16* __restrict__ mixed) {
  int blk = blockIdx.x;
  int c = blk & 31, h = (blk >> 5) & 15, b = blk >> 9;
  int f = threadIdx.x;
  float d = fminf(fmaxf(decay[h], 0.9f), 1.0f);
  float r = powf(d, 0.25f);
  float rl = powf(r, (float)SC_L);
  int cb = blk - c;
  float S = 0.f;
  for (int cc = 0; cc < c; cc++) S = rl * S + carry[(cb + cc) * 64 + f];
  size_t base = ((size_t)b * TT + c * SC_L) * EE + h * HHD + f;
  const float* mw = mix_w + h * TT + c * SC_L;
  const float* mb = mix_b + h * TT + c * SC_L;
  bool isRow = (h >= 8);
  for (int t = 0; t < SC_L; t++) {
    float pv = bf2f(p[base + (size_t)t * EE]);
    float q = isRow ? mw[t] * pv : pv;
    S = r * S + q;
    float val = (isRow ? S : mw[t] * S) + mb[t];
    mixed[base + (size_t)t * EE] = f2bf(val);
  }
}

extern "C" void kernel_launch(void* const* d_in, const int* in_sizes, int n_in,
                              void* d_out, int out_size, void* d_ws, size_t ws_size,
                              hipStream_t stream) {
  const float* x = (const float*)d_in[0];
  const float* w_proj = (const float*)d_in[1];
  const float* b_proj = (const float*)d_in[2];
  const float* mix_w = (const float*)d_in[3];
  const float* mix_b = (const float*)d_in[4];
  const float* decay = (const float*)d_in[5];
  const float* out_w = (const float*)d_in[6];
  const float* out_b = (const float*)d_in[7];
  const float* ln1_g = (const float*)d_in[8];
  const float* ln1_b = (const float*)d_in[9];
  const float* ln2_g = (const float*)d_in[10];
  const float* ln2_b = (const float*)d_in[11];
  const float* ff_w1 = (const float*)d_in[12];
  const float* ff_b1 = (const float*)d_in[13];
  const float* ff_w2 = (const float*)d_in[14];
  const float* ff_b2 = (const float*)d_in[15];
  float* out = (float*)d_out;

  // ws layout (MiB): [0,2)Wp [2,4)Wo [4,12)W1 [12,20)W2 [20,52)mixed/g
  //                  [52,180)u (h at 52, p at 84) [180,181)carry
  char* ws = (char*)d_ws;
  const size_t MiB = 1ull << 20;
  u16* wWp = (u16*)(ws + 0 * MiB);
  u16* wWo = (u16*)(ws + 2 * MiB);
  u16* wW1 = (u16*)(ws + 4 * MiB);
  u16* wW2 = (u16*)(ws + 12 * MiB);
  u16* wMix = (u16*)(ws + 20 * MiB);
  u16* wH = (u16*)(ws + 52 * MiB);
  u16* wP = (u16*)(ws + 84 * MiB);
  u16* wU = (u16*)(ws + 52 * MiB);
  float* wCarry = (float*)(ws + 180 * MiB);

  dim3 tb(32, 8);
  transpose_to_bf16<<<dim3(2, 32, 16), tb, 0, stream>>>(w_proj, wWp, 1024, 64,
                                                        65536L, 65536L);
  transpose_to_bf16<<<dim3(32, 32, 1), tb, 0, stream>>>(out_w, wWo, 1024, 1024, 0L, 0L);
  transpose_to_bf16<<<dim3(128, 32, 1), tb, 0, stream>>>(ff_w1, wW1, 1024, 4096, 0L, 0L);
  transpose_to_bf16<<<dim3(32, 128, 1), tb, 0, stream>>>(ff_w2, wW2, 4096, 1024, 0L, 0L);

  ln_to_bf16<<<dim3(MROWS), dim3(256), 0, stream>>>(x, ln1_g, ln1_b, wH);

  // G1: px=4 (B 2MB fully L2/XCD), gxp=1, byper=8
  gemm256pc<0><<<dim3(4, 64), dim3(576), 0, stream>>>(
      wH, wWp, b_proj, (const float*)nullptr, (void*)wP, MROWS, 1024, 1024,
      4, 1, 8);

  scan_carry<<<dim3(4096), dim3(64), 0, stream>>>(wP, mix_w, decay, wCarry);
  scan_apply<<<dim3(4096), dim3(64), 0, stream>>>(wP, mix_w, mix_b, decay, wCarry, wMix);

  // G2: same shape as G1
  gemm256pc<1><<<dim3(4, 64), dim3(576), 0, stream>>>(
      wMix, wWo, out_b, x, (void*)out, MROWS, 1024, 1024,
      4, 1, 8);

  ln_to_bf16<<<dim3(MROWS), dim3(256), 0, stream>>>(out, ln2_g, ln2_b, wMix);

  // G3: px=4, gxp=4, byper=32
  gemm256pc<2><<<dim3(16, 64), dim3(576), 0, stream>>>(
      wMix, wW1, ff_b1, (const float*)nullptr, (void*)wU, MROWS, 4096, 1024,
      4, 4, 32);

  // G4: px=2, gxp=2, byper=16
  gemm256pc<1><<<dim3(4, 64), dim3(576), 0, stream>>>(
      wU, wW2, ff_b2, out, (void*)out, MROWS, 1024, 4096,
      2, 2, 16);
}

// Round 12
// 523.953 us; speedup vs baseline: 1.3720x; 1.3328x over previous
//
#include <hip/hip_runtime.h>

// MixerBlock: B=8, T=2048, E=1024, H=16, HD=64, DFF=4096, DC=4
// GEMM r12: 256x256 tile, BK=64, **16 waves (1024 thr, 4Mx4N, 64x64/wave)**,
// dbuf 128 KiB LDS, free-run loop (r8): STAGE_ALL(t+1) -> vmcnt(4) ->
// s_barrier -> compute (compiler-scheduled ds_read+MFMA, ks-outer to keep
// live frags ~20 regs) -> s_barrier. 1024-thr block forces <=128 VGPR/wave
// => 4 waves/SIMD: read/MFMA phases of co-resident waves skew within the
// barrier window so the LDS pipe and MFMA pipe overlap (m114 mechanism) —
// all prior 256^2 builds had only 2 waves/SIMD and time-sliced the pipes.
// LDS layout (proven 0-conflict): per matrix [256 rows][8 slots of 8 bf16],
// LDS slot s holds global slot s^(row&7) via pre-swizzled source (rule #21);
// read slot = (ks*4+lk)^(l15&7). Supertile XCD swizzle as r6.

#define TT 2048
#define EE 1024
#define HHD 64
#define MROWS 16384
#define SC_L 64

typedef __bf16 bf16x8 __attribute__((ext_vector_type(8)));
typedef float f32x4 __attribute__((ext_vector_type(4)));
typedef unsigned short u16;
typedef unsigned int u32;

__device__ __forceinline__ u16 f2bf(float f) {
  u32 u = __builtin_bit_cast(u32, f);
  u += 0x7FFFu + ((u >> 16) & 1u);      // round-to-nearest-even
  return (u16)(u >> 16);
}
__device__ __forceinline__ float bf2f(u16 s) {
  u32 u = ((u32)s) << 16;
  return __builtin_bit_cast(float, u);
}
__device__ __forceinline__ float gelu_f(float x) {
  float x2 = x * x;
  float e = -1.5957691216057308f * x * __builtin_fmaf(0.044715f, x2, 1.0f);
  return x * __builtin_amdgcn_rcpf(1.0f + __expf(e));
}
__device__ __forceinline__ void gload_lds16(const void* g, void* l) {
  __builtin_amdgcn_global_load_lds(
      (const __attribute__((address_space(1))) u32*)g,
      (__attribute__((address_space(3))) u32*)l, 16, 0, 0);
}
__device__ __forceinline__ void wg_barrier() {
  asm volatile("" ::: "memory");
  __builtin_amdgcn_s_barrier();
  asm volatile("" ::: "memory");
}

// ---------------- weight transpose + cast
__global__ __launch_bounds__(256) void transpose_to_bf16(
    const float* __restrict__ src, u16* __restrict__ dst, int R, int C,
    long sbs, long dbs) {
  __shared__ float tile[32][33];
  src += (long)blockIdx.z * sbs;
  dst += (long)blockIdx.z * dbs;
  int c0 = blockIdx.x * 32, r0 = blockIdx.y * 32;
  int tx = threadIdx.x, ty = threadIdx.y;
#pragma unroll
  for (int i = 0; i < 4; i++)
    tile[ty + i * 8][tx] = src[(long)(r0 + ty + i * 8) * C + c0 + tx];
  __syncthreads();
#pragma unroll
  for (int i = 0; i < 4; i++)
    dst[(long)(c0 + ty + i * 8) * R + r0 + tx] = f2bf(tile[tx][ty + i * 8]);
}

// ---------------- LayerNorm over E=1024
__global__ __launch_bounds__(256) void ln_to_bf16(
    const float* __restrict__ x, const float* __restrict__ gam,
    const float* __restrict__ bet, u16* __restrict__ y) {
  int row = blockIdx.x;
  int tid = threadIdx.x;
  float4 v = ((const float4*)x)[row * 256 + tid];
  float s = v.x + v.y + v.z + v.w;
  float s2 = v.x * v.x + v.y * v.y + v.z * v.z + v.w * v.w;
#pragma unroll
  for (int off = 1; off < 64; off <<= 1) {
    s += __shfl_xor(s, off);
    s2 += __shfl_xor(s2, off);
  }
  __shared__ float red[8];
  int w = tid >> 6;
  if ((tid & 63) == 0) { red[w] = s; red[4 + w] = s2; }
  __syncthreads();
  s = red[0] + red[1] + red[2] + red[3];
  s2 = red[4] + red[5] + red[6] + red[7];
  float mu = s * (1.0f / 1024.0f);
  float var = s2 * (1.0f / 1024.0f) - mu * mu;
  float rstd = rsqrtf(var + 1e-5f);
  int e0 = tid * 4;
  ushort4 o;
  o.x = f2bf((v.x - mu) * rstd * gam[e0 + 0] + bet[e0 + 0]);
  o.y = f2bf((v.y - mu) * rstd * gam[e0 + 1] + bet[e0 + 1]);
  o.z = f2bf((v.z - mu) * rstd * gam[e0 + 2] + bet[e0 + 2]);
  o.w = f2bf((v.w - mu) * rstd * gam[e0 + 3] + bet[e0 + 3]);
  ((ushort4*)y)[row * 256 + tid] = o;
}

// ---------------- bf16 GEMM, 256x256, BK=64, 16 waves, free-run counted-vmcnt.
// A: (M x K) bf16 rm. Bt: (N x K) bf16 rm.
// LDS buffer c at c*32768 (u16): A [0,16384), B [16384,32768); row = 64 u16.
// EPI 0: bf16 = acc+bias ; 1: f32 = acc+bias+res ; 2: bf16 = gelu(acc+bias)
template <int EPI>
__global__ __launch_bounds__(1024) void gemm256w16(
    const u16* __restrict__ A, const u16* __restrict__ Bt,
    const float* __restrict__ bias, const float* __restrict__ res, void* outp,
    int M, int N, int K, int px, int gxp, int byper) {
  __shared__ u16 lds[65536];  // 128 KiB
  const int tid = threadIdx.x;
  const int w = tid >> 6, lane = tid & 63;
  const int wm = w >> 2, wn = w & 3;            // 4x4 wave grid, 64x64/wave
  const int l15 = lane & 15, lk = lane >> 4;

  // T1: L2-locality supertile swizzle (bijective; nwg % 8 == 0 always)
  const int gx = (int)gridDim.x;
  const int bid = (int)blockIdx.y * gx + (int)blockIdx.x;
  const int xcd = bid & 7, i = bid >> 3;
  const int bx = (xcd % gxp) * px + (i % px);
  const int by = (xcd / gxp) * byper + (i / px);
  const int m0 = by * 256, n0 = bx * 256;

  // Staging: one issue = 1024 thr x 16B = 128 rows (8 slots/row). Thread t:
  // row t>>3, slot t&7, global slot pre-swizzled by row&7 = (t>>3)&7.
  const int srow = w * 8 + (lane >> 3);         // row within 128-row issue
  const int sslot = (lane & 7) ^ (lane >> 3);
  const u16* aS = A + (size_t)(m0 + srow) * K + sslot * 8;
  const u16* bS = Bt + (size_t)(n0 + srow) * K + sslot * 8;

  f32x4 acc[4][4];
  const f32x4 z = {0.f, 0.f, 0.f, 0.f};
#pragma unroll
  for (int mi = 0; mi < 4; mi++)
#pragma unroll
    for (int ni = 0; ni < 4; ni++) acc[mi][ni] = z;

  const int sl0 = (lk ^ (l15 & 7)) * 8;        // u16 offset of ks0 slot
  const int sl1 = ((4 + lk) ^ (l15 & 7)) * 8;  // ks1

#define STAGE_ALL(C, KT) { \
    u16* lb = lds + (C) * 32768 + w * 512; \
    gload_lds16(aS + (KT), lb); \
    gload_lds16(aS + (size_t)128 * K + (KT), lb + 8192); \
    gload_lds16(bS + (KT), lb + 16384); \
    gload_lds16(bS + (size_t)128 * K + (KT), lb + 24576); }

  const int nt = K >> 6;
  STAGE_ALL(0, 0);  // prologue: 4 outstanding for tile 0

  for (int t = 0; t < nt; ++t) {
    const int cur = t & 1, nx = cur ^ 1;
    if (t + 1 < nt) {
      STAGE_ALL(nx, (t + 1) << 6);                      // 4 more in flight
      asm volatile("s_waitcnt vmcnt(4)" ::: "memory");  // forces tile t's
    } else {
      asm volatile("s_waitcnt vmcnt(0)" ::: "memory");  // last tile drain
    }
    wg_barrier();  // all waves' t-stages resident; t-1 readers long done

    // ---- compute tile t from buf cur: ks-outer, low frag pressure ----
    const u16* lA = lds + cur * 32768 + (wm * 64 + l15) * 64;
    const u16* lB = lds + cur * 32768 + 16384 + (wn * 64 + l15) * 64;
#pragma unroll
    for (int ks = 0; ks < 2; ks++) {
      const int sl = ks ? sl1 : sl0;
      bf16x8 bq[4];
#pragma unroll
      for (int ni = 0; ni < 4; ni++)
        bq[ni] = *(const bf16x8*)(lB + ni * 1024 + sl);
      __builtin_amdgcn_s_setprio(1);
#pragma unroll
      for (int mi = 0; mi < 4; mi++) {
        bf16x8 af = *(const bf16x8*)(lA + mi * 1024 + sl);
#pragma unroll
        for (int ni = 0; ni < 4; ni++)
          acc[mi][ni] = __builtin_amdgcn_mfma_f32_16x16x32_bf16(af, bq[ni],
                                                                acc[mi][ni], 0, 0, 0);
      }
      __builtin_amdgcn_s_setprio(0);
    }
    wg_barrier();  // readers of 'cur' done before t+1's stages overwrite cur
  }
#undef STAGE_ALL

#pragma unroll
  for (int mi = 0; mi < 4; mi++) {
#pragma unroll
    for (int ni = 0; ni < 4; ni++) {
      int n = n0 + wn * 64 + ni * 16 + l15;       // C/D: col = lane&15
      float bvv = bias[n];
#pragma unroll
      for (int r = 0; r < 4; r++) {
        int m = m0 + wm * 64 + mi * 16 + lk * 4 + r;  // row = (lane>>4)*4 + reg
        size_t idx = (size_t)m * N + n;
        float v = acc[mi][ni][r] + bvv;
        if (EPI == 0) {
          ((u16*)outp)[idx] = f2bf(v);
        } else if (EPI == 1) {
          ((float*)outp)[idx] = v + res[idx];
        } else {
          ((u16*)outp)[idx] = f2bf(gelu_f(v));
        }
      }
    }
  }
}

// ---------------- causal decay scan
__global__ __launch_bounds__(64) void scan_carry(
    const u16* __restrict__ p, const float* __restrict__ mix_w,
    const float* __restrict__ decay, float* __restrict__ carry) {
  int blk = blockIdx.x;
  int c = blk & 31, h = (blk >> 5) & 15, b = blk >> 9;
  int f = threadIdx.x;
  float d = fminf(fmaxf(decay[h], 0.9f), 1.0f);
  float r = powf(d, 0.25f);
  size_t base = ((size_t)b * TT + c * SC_L) * EE + h * HHD + f;
  const float* mw = mix_w + h * TT + c * SC_L;
  bool isRow = (h >= 8);
  float S = 0.f;
#pragma unroll 4
  for (int t = 0; t < SC_L; t++) {
    float pv = bf2f(p[base + (size_t)t * EE]);
    float q = isRow ? mw[t] * pv : pv;
    S = r * S + q;
  }
  carry[blk * 64 + f] = S;
}

__global__ __launch_bounds__(64) void scan_apply(
    const u16* __restrict__ p, const float* __restrict__ mix_w,
    const float* __restrict__ mix_b, const float* __restrict__ decay,
    const float* __restrict__ carry, u16* __restrict__ mixed) {
  int blk = blockIdx.x;
  int c = blk & 31, h = (blk >> 5) & 15, b = blk >> 9;
  int f = threadIdx.x;
  float d = fminf(fmaxf(decay[h], 0.9f), 1.0f);
  float r = powf(d, 0.25f);
  float rl = powf(r, (float)SC_L);
  int cb = blk - c;
  float S = 0.f;
  for (int cc = 0; cc < c; cc++) S = rl * S + carry[(cb + cc) * 64 + f];
  size_t base = ((size_t)b * TT + c * SC_L) * EE + h * HHD + f;
  const float* mw = mix_w + h * TT + c * SC_L;
  const float* mb = mix_b + h * TT + c * SC_L;
  bool isRow = (h >= 8);
  for (int t = 0; t < SC_L; t++) {
    float pv = bf2f(p[base + (size_t)t * EE]);
    float q = isRow ? mw[t] * pv : pv;
    S = r * S + q;
    float val = (isRow ? S : mw[t] * S) + mb[t];
    mixed[base + (size_t)t * EE] = f2bf(val);
  }
}

extern "C" void kernel_launch(void* const* d_in, const int* in_sizes, int n_in,
                              void* d_out, int out_size, void* d_ws, size_t ws_size,
                              hipStream_t stream) {
  const float* x = (const float*)d_in[0];
  const float* w_proj = (const float*)d_in[1];
  const float* b_proj = (const float*)d_in[2];
  const float* mix_w = (const float*)d_in[3];
  const float* mix_b = (const float*)d_in[4];
  const float* decay = (const float*)d_in[5];
  const float* out_w = (const float*)d_in[6];
  const float* out_b = (const float*)d_in[7];
  const float* ln1_g = (const float*)d_in[8];
  const float* ln1_b = (const float*)d_in[9];
  const float* ln2_g = (const float*)d_in[10];
  const float* ln2_b = (const float*)d_in[11];
  const float* ff_w1 = (const float*)d_in[12];
  const float* ff_b1 = (const float*)d_in[13];
  const float* ff_w2 = (const float*)d_in[14];
  const float* ff_b2 = (const float*)d_in[15];
  float* out = (float*)d_out;

  // ws layout (MiB): [0,2)Wp [2,4)Wo [4,12)W1 [12,20)W2 [20,52)mixed/g
  //                  [52,180)u (h at 52, p at 84) [180,181)carry
  char* ws = (char*)d_ws;
  const size_t MiB = 1ull << 20;
  u16* wWp = (u16*)(ws + 0 * MiB);
  u16* wWo = (u16*)(ws + 2 * MiB);
  u16* wW1 = (u16*)(ws + 4 * MiB);
  u16* wW2 = (u16*)(ws + 12 * MiB);
  u16* wMix = (u16*)(ws + 20 * MiB);
  u16* wH = (u16*)(ws + 52 * MiB);
  u16* wP = (u16*)(ws + 84 * MiB);
  u16* wU = (u16*)(ws + 52 * MiB);
  float* wCarry = (float*)(ws + 180 * MiB);

  dim3 tb(32, 8);
  transpose_to_bf16<<<dim3(2, 32, 16), tb, 0, stream>>>(w_proj, wWp, 1024, 64,
                                                        65536L, 65536L);
  transpose_to_bf16<<<dim3(32, 32, 1), tb, 0, stream>>>(out_w, wWo, 1024, 1024, 0L, 0L);
  transpose_to_bf16<<<dim3(128, 32, 1), tb, 0, stream>>>(ff_w1, wW1, 1024, 4096, 0L, 0L);
  transpose_to_bf16<<<dim3(32, 128, 1), tb, 0, stream>>>(ff_w2, wW2, 4096, 1024, 0L, 0L);

  ln_to_bf16<<<dim3(MROWS), dim3(256), 0, stream>>>(x, ln1_g, ln1_b, wH);

  // G1: px=4 (B 2MB fully L2/XCD), gxp=1, byper=8
  gemm256w16<0><<<dim3(4, 64), dim3(1024), 0, stream>>>(
      wH, wWp, b_proj, (const float*)nullptr, (void*)wP, MROWS, 1024, 1024,
      4, 1, 8);

  scan_carry<<<dim3(4096), dim3(64), 0, stream>>>(wP, mix_w, decay, wCarry);
  scan_apply<<<dim3(4096), dim3(64), 0, stream>>>(wP, mix_w, mix_b, decay, wCarry, wMix);

  // G2: same shape as G1
  gemm256w16<1><<<dim3(4, 64), dim3(1024), 0, stream>>>(
      wMix, wWo, out_b, x, (void*)out, MROWS, 1024, 1024,
      4, 1, 8);

  ln_to_bf16<<<dim3(MROWS), dim3(256), 0, stream>>>(out, ln2_g, ln2_b, wMix);

  // G3: px=4, gxp=4, byper=32
  gemm256w16<2><<<dim3(16, 64), dim3(1024), 0, stream>>>(
      wMix, wW1, ff_b1, (const float*)nullptr, (void*)wU, MROWS, 4096, 1024,
      4, 4, 32);

  // G4: px=2, gxp=2, byper=16
  gemm256w16<1><<<dim3(4, 64), dim3(1024), 0, stream>>>(
      wU, wW2, ff_b2, out, (void*)out, MROWS, 1024, 4096,
      2, 2, 16);
}

// Round 13
// 520.371 us; speedup vs baseline: 1.3814x; 1.0069x over previous
//
#include <hip/hip_runtime.h>

// MixerBlock: B=8, T=2048, E=1024, H=16, HD=64, DFF=4096, DC=4
// GEMM r13: 256x256 tile, BK=32, 8 waves (2Mx4N), QUAD-buffered LDS
// (4 x 32 KiB), ONE barrier per K-tile:
//   per tile t: STAGE(buf[(t+2)&3], t+2)  (4 gloads/thread)
//               vmcnt(8)  (forces own tile-t loads; 2-tile slack)
//               s_barrier (all waves' t-data resident)
//               compute tile t  (NO trailing barrier -> waves desync, LDS
//               reads of one wave overlap MFMAs of another)
// Ledger (audited): stage(t+2) writes buf used by tile t-2, whose readers all
// finished before barrier B_{t-1} < issue point; compute(t) reads data forced
// by every wave's own vmcnt(8) before B_t. Tail: t=nt-2 vmcnt(4), t=nt-1
// vmcnt(0). LDS row = 64 B (4 slots of 16 B); slot s holds global slot
// s ^ ((row>>1)&3) via pre-swizzled source (rule #21); read sl = lk^((l15>>1)&3)
// -> uniform 2-way bank groups (free, m136).
// Scans r13: vectorized 8 f/thread (short8), grid 512 x 64.

#define TT 2048
#define EE 1024
#define HHD 64
#define MROWS 16384
#define SC_L 64

typedef __bf16 bf16x8 __attribute__((ext_vector_type(8)));
typedef float f32x4 __attribute__((ext_vector_type(4)));
typedef unsigned short u16;
typedef unsigned int u32;
typedef u16 u16x8 __attribute__((ext_vector_type(8)));

__device__ __forceinline__ u16 f2bf(float f) {
  u32 u = __builtin_bit_cast(u32, f);
  u += 0x7FFFu + ((u >> 16) & 1u);      // round-to-nearest-even
  return (u16)(u >> 16);
}
__device__ __forceinline__ float bf2f(u16 s) {
  u32 u = ((u32)s) << 16;
  return __builtin_bit_cast(float, u);
}
__device__ __forceinline__ float gelu_f(float x) {
  float x2 = x * x;
  float e = -1.5957691216057308f * x * __builtin_fmaf(0.044715f, x2, 1.0f);
  return x * __builtin_amdgcn_rcpf(1.0f + __expf(e));
}
__device__ __forceinline__ void gload_lds16(const void* g, void* l) {
  __builtin_amdgcn_global_load_lds(
      (const __attribute__((address_space(1))) u32*)g,
      (__attribute__((address_space(3))) u32*)l, 16, 0, 0);
}
__device__ __forceinline__ void wg_barrier() {
  asm volatile("" ::: "memory");
  __builtin_amdgcn_s_barrier();
  asm volatile("" ::: "memory");
}

// ---------------- weight transpose + cast
__global__ __launch_bounds__(256) void transpose_to_bf16(
    const float* __restrict__ src, u16* __restrict__ dst, int R, int C,
    long sbs, long dbs) {
  __shared__ float tile[32][33];
  src += (long)blockIdx.z * sbs;
  dst += (long)blockIdx.z * dbs;
  int c0 = blockIdx.x * 32, r0 = blockIdx.y * 32;
  int tx = threadIdx.x, ty = threadIdx.y;
#pragma unroll
  for (int i = 0; i < 4; i++)
    tile[ty + i * 8][tx] = src[(long)(r0 + ty + i * 8) * C + c0 + tx];
  __syncthreads();
#pragma unroll
  for (int i = 0; i < 4; i++)
    dst[(long)(c0 + ty + i * 8) * R + r0 + tx] = f2bf(tile[tx][ty + i * 8]);
}

// ---------------- LayerNorm over E=1024
__global__ __launch_bounds__(256) void ln_to_bf16(
    const float* __restrict__ x, const float* __restrict__ gam,
    const float* __restrict__ bet, u16* __restrict__ y) {
  int row = blockIdx.x;
  int tid = threadIdx.x;
  float4 v = ((const float4*)x)[row * 256 + tid];
  float s = v.x + v.y + v.z + v.w;
  float s2 = v.x * v.x + v.y * v.y + v.z * v.z + v.w * v.w;
#pragma unroll
  for (int off = 1; off < 64; off <<= 1) {
    s += __shfl_xor(s, off);
    s2 += __shfl_xor(s2, off);
  }
  __shared__ float red[8];
  int w = tid >> 6;
  if ((tid & 63) == 0) { red[w] = s; red[4 + w] = s2; }
  __syncthreads();
  s = red[0] + red[1] + red[2] + red[3];
  s2 = red[4] + red[5] + red[6] + red[7];
  float mu = s * (1.0f / 1024.0f);
  float var = s2 * (1.0f / 1024.0f) - mu * mu;
  float rstd = rsqrtf(var + 1e-5f);
  int e0 = tid * 4;
  ushort4 o;
  o.x = f2bf((v.x - mu) * rstd * gam[e0 + 0] + bet[e0 + 0]);
  o.y = f2bf((v.y - mu) * rstd * gam[e0 + 1] + bet[e0 + 1]);
  o.z = f2bf((v.z - mu) * rstd * gam[e0 + 2] + bet[e0 + 2]);
  o.w = f2bf((v.w - mu) * rstd * gam[e0 + 3] + bet[e0 + 3]);
  ((ushort4*)y)[row * 256 + tid] = o;
}

// ---------------- bf16 GEMM, 256x256, BK=32, quad-buffered, 1 barrier/tile.
// A: (M x K) bf16 rm. Bt: (N x K) bf16 rm.
// LDS buf q at q*16384 (u16): A [0,8192) rows 0-255 x 32; B [8192,16384).
// EPI 0: bf16 = acc+bias ; 1: f32 = acc+bias+res ; 2: bf16 = gelu(acc+bias)
template <int EPI>
__global__ __launch_bounds__(512, 1) void gemm256q(
    const u16* __restrict__ A, const u16* __restrict__ Bt,
    const float* __restrict__ bias, const float* __restrict__ res, void* outp,
    int M, int N, int K, int px, int gxp, int byper) {
  __shared__ u16 lds[65536];  // 128 KiB = 4 x 32 KiB buffers
  const int tid = threadIdx.x;
  const int w = tid >> 6, lane = tid & 63;
  const int wm = w >> 2, wn = w & 3;
  const int l15 = lane & 15, lk = lane >> 4;

  // T1: L2-locality supertile swizzle (bijective; nwg % 8 == 0 always)
  const int gx = (int)gridDim.x;
  const int bid = (int)blockIdx.y * gx + (int)blockIdx.x;
  const int xcd = bid & 7, i = bid >> 3;
  const int bx = (xcd % gxp) * px + (i % px);
  const int by = (xcd / gxp) * byper + (i / px);
  const int m0 = by * 256, n0 = bx * 256;

  // Staging: thread t -> row srow = t>>2 (0..127, +128 via 2nd load), LDS
  // slot t&3; global slot pre-swizzled by (row>>1)&3.
  const int srow = w * 16 + (lane >> 2);
  const int gslot = (lane & 3) ^ ((srow >> 1) & 3);
  const u16* aS = A + (size_t)(m0 + srow) * K + gslot * 8;
  const u16* aS2 = A + (size_t)(m0 + 128 + srow) * K +
                   (((lane & 3) ^ (((128 + srow) >> 1) & 3)) * 8);
  const u16* bS = Bt + (size_t)(n0 + srow) * K + gslot * 8;
  const u16* bS2 = Bt + (size_t)(n0 + 128 + srow) * K +
                   (((lane & 3) ^ (((128 + srow) >> 1) & 3)) * 8);

  f32x4 acc[8][4];
  const f32x4 z = {0.f, 0.f, 0.f, 0.f};
#pragma unroll
  for (int mi = 0; mi < 8; mi++)
#pragma unroll
    for (int ni = 0; ni < 4; ni++) acc[mi][ni] = z;

  // Read-side swizzle: (row>>1)&3 == (l15>>1)&3 for all mi/ni (strides 16).
  const int sl = (lk ^ ((l15 >> 1) & 3)) * 8;  // u16 offset within row

#define STAGE(BUF, T_) { \
    u16* lb = lds + (BUF) * 16384 + w * 512; \
    const int kt = (T_) << 5; \
    gload_lds16(aS + kt, lb); \
    gload_lds16(aS2 + kt, lb + 4096); \
    gload_lds16(bS + kt, lb + 8192); \
    gload_lds16(bS2 + kt, lb + 12288); }

  const int nt = K >> 5;
  STAGE(0, 0);
  STAGE(1, 1);

  for (int t = 0; t < nt; ++t) {
    if (t + 2 < nt) {
      STAGE((t + 2) & 3, t + 2);
      asm volatile("s_waitcnt vmcnt(8)" ::: "memory");   // forces tile t's own
    } else if (t + 1 < nt) {
      asm volatile("s_waitcnt vmcnt(4)" ::: "memory");
    } else {
      asm volatile("s_waitcnt vmcnt(0)" ::: "memory");
    }
    wg_barrier();  // ONLY barrier this tile: everyone's t-data resident;
                   // also fences next iteration's stage into buf[t-1].

    const u16* lA = lds + (t & 3) * 16384;
    const u16* lB = lA + 8192;
    bf16x8 bq[4];
    {
      const u16* bp = lB + (wn * 64 + l15) * 32 + sl;
#pragma unroll
      for (int ni = 0; ni < 4; ni++) bq[ni] = *(const bf16x8*)(bp + ni * 512);
    }
    const u16* ap = lA + (wm * 128 + l15) * 32 + sl;
    __builtin_amdgcn_s_setprio(1);
#pragma unroll
    for (int mi = 0; mi < 8; mi++) {
      bf16x8 af = *(const bf16x8*)(ap + mi * 512);
#pragma unroll
      for (int ni = 0; ni < 4; ni++)
        acc[mi][ni] = __builtin_amdgcn_mfma_f32_16x16x32_bf16(af, bq[ni],
                                                              acc[mi][ni], 0, 0, 0);
    }
    __builtin_amdgcn_s_setprio(0);
    // no trailing barrier: next tile's stage targets buf[(t+3)&3], never a
    // buffer any wave (<=1 tile behind) can still be reading.
  }
#undef STAGE

#pragma unroll
  for (int mi = 0; mi < 8; mi++) {
#pragma unroll
    for (int ni = 0; ni < 4; ni++) {
      int n = n0 + wn * 64 + ni * 16 + l15;       // C/D: col = lane&15
      float bvv = bias[n];
#pragma unroll
      for (int r = 0; r < 4; r++) {
        int m = m0 + wm * 128 + mi * 16 + lk * 4 + r;  // row = (lane>>4)*4 + reg
        size_t idx = (size_t)m * N + n;
        float v = acc[mi][ni][r] + bvv;
        if (EPI == 0) {
          ((u16*)outp)[idx] = f2bf(v);
        } else if (EPI == 1) {
          ((float*)outp)[idx] = v + res[idx];
        } else {
          ((u16*)outp)[idx] = f2bf(gelu_f(v));
        }
      }
    }
  }
}

// ---------------- causal decay scan, vectorized 8 f/thread.
// chunk = (b,h,c); 8 threads per chunk; grid 512 x 64.
__global__ __launch_bounds__(64) void scan_carry(
    const u16* __restrict__ p, const float* __restrict__ mix_w,
    const float* __restrict__ decay, float* __restrict__ carry) {
  int chunk = blockIdx.x * 8 + (threadIdx.x >> 3);
  int fg = threadIdx.x & 7;
  int c = chunk & 31, h = (chunk >> 5) & 15, b = chunk >> 9;
  float d = fminf(fmaxf(decay[h], 0.9f), 1.0f);
  float r = powf(d, 0.25f);
  size_t base = (((size_t)b * TT + c * SC_L) * EE + h * HHD + fg * 8) >> 3;
  const u16x8* p8 = (const u16x8*)p;
  const float* mw = mix_w + h * TT + c * SC_L;
  bool isRow = (h >= 8);
  float S[8] = {0.f, 0.f, 0.f, 0.f, 0.f, 0.f, 0.f, 0.f};
  for (int t = 0; t < SC_L; t++) {
    u16x8 v = p8[base + (size_t)t * (EE / 8)];
    float wv = isRow ? mw[t] : 1.0f;
#pragma unroll
    for (int j = 0; j < 8; j++) S[j] = r * S[j] + wv * bf2f(v[j]);
  }
  float* cp = carry + chunk * 64 + fg * 8;
#pragma unroll
  for (int j = 0; j < 8; j++) cp[j] = S[j];
}

__global__ __launch_bounds__(64) void scan_apply(
    const u16* __restrict__ p, const float* __restrict__ mix_w,
    const float* __restrict__ mix_b, const float* __restrict__ decay,
    const float* __restrict__ carry, u16* __restrict__ mixed) {
  int chunk = blockIdx.x * 8 + (threadIdx.x >> 3);
  int fg = threadIdx.x & 7;
  int c = chunk & 31, h = (chunk >> 5) & 15, b = chunk >> 9;
  float d = fminf(fmaxf(decay[h], 0.9f), 1.0f);
  float r = powf(d, 0.25f);
  float rl = powf(r, (float)SC_L);
  int cb = chunk - c;
  float S[8] = {0.f, 0.f, 0.f, 0.f, 0.f, 0.f, 0.f, 0.f};
  for (int cc = 0; cc < c; cc++) {
    const float* cp = carry + (cb + cc) * 64 + fg * 8;
#pragma unroll
    for (int j = 0; j < 8; j++) S[j] = rl * S[j] + cp[j];
  }
  size_t base = (((size_t)b * TT + c * SC_L) * EE + h * HHD + fg * 8) >> 3;
  const u16x8* p8 = (const u16x8*)p;
  u16x8* m8 = (u16x8*)mixed;
  const float* mw = mix_w + h * TT + c * SC_L;
  const float* mb = mix_b + h * TT + c * SC_L;
  bool isRow = (h >= 8);
  for (int t = 0; t < SC_L; t++) {
    u16x8 v = p8[base + (size_t)t * (EE / 8)];
    float wq = isRow ? mw[t] : 1.0f;
    float wo = isRow ? 1.0f : mw[t];
    float bb = mb[t];
    u16x8 o;
#pragma unroll
    for (int j = 0; j < 8; j++) {
      S[j] = r * S[j] + wq * bf2f(v[j]);
      o[j] = f2bf(wo * S[j] + bb);
    }
    m8[base + (size_t)t * (EE / 8)] = o;
  }
}

extern "C" void kernel_launch(void* const* d_in, const int* in_sizes, int n_in,
                              void* d_out, int out_size, void* d_ws, size_t ws_size,
                              hipStream_t stream) {
  const float* x = (const float*)d_in[0];
  const float* w_proj = (const float*)d_in[1];
  const float* b_proj = (const float*)d_in[2];
  const float* mix_w = (const float*)d_in[3];
  const float* mix_b = (const float*)d_in[4];
  const float* decay = (const float*)d_in[5];
  const float* out_w = (const float*)d_in[6];
  const float* out_b = (const float*)d_in[7];
  const float* ln1_g = (const float*)d_in[8];
  const float* ln1_b = (const float*)d_in[9];
  const float* ln2_g = (const float*)d_in[10];
  const float* ln2_b = (const float*)d_in[11];
  const float* ff_w1 = (const float*)d_in[12];
  const float* ff_b1 = (const float*)d_in[13];
  const float* ff_w2 = (const float*)d_in[14];
  const float* ff_b2 = (const float*)d_in[15];
  float* out = (float*)d_out;

  // ws layout (MiB): [0,2)Wp [2,4)Wo [4,12)W1 [12,20)W2 [20,52)mixed/g
  //                  [52,180)u (h at 52, p at 84) [180,181)carry
  char* ws = (char*)d_ws;
  const size_t MiB = 1ull << 20;
  u16* wWp = (u16*)(ws + 0 * MiB);
  u16* wWo = (u16*)(ws + 2 * MiB);
  u16* wW1 = (u16*)(ws + 4 * MiB);
  u16* wW2 = (u16*)(ws + 12 * MiB);
  u16* wMix = (u16*)(ws + 20 * MiB);
  u16* wH = (u16*)(ws + 52 * MiB);
  u16* wP = (u16*)(ws + 84 * MiB);
  u16* wU = (u16*)(ws + 52 * MiB);
  float* wCarry = (float*)(ws + 180 * MiB);

  dim3 tb(32, 8);
  transpose_to_bf16<<<dim3(2, 32, 16), tb, 0, stream>>>(w_proj, wWp, 1024, 64,
                                                        65536L, 65536L);
  transpose_to_bf16<<<dim3(32, 32, 1), tb, 0, stream>>>(out_w, wWo, 1024, 1024, 0L, 0L);
  transpose_to_bf16<<<dim3(128, 32, 1), tb, 0, stream>>>(ff_w1, wW1, 1024, 4096, 0L, 0L);
  transpose_to_bf16<<<dim3(32, 128, 1), tb, 0, stream>>>(ff_w2, wW2, 4096, 1024, 0L, 0L);

  ln_to_bf16<<<dim3(MROWS), dim3(256), 0, stream>>>(x, ln1_g, ln1_b, wH);

  // G1: px=4 (B 2MB fully L2/XCD), gxp=1, byper=8
  gemm256q<0><<<dim3(4, 64), dim3(512), 0, stream>>>(
      wH, wWp, b_proj, (const float*)nullptr, (void*)wP, MROWS, 1024, 1024,
      4, 1, 8);

  scan_carry<<<dim3(512), dim3(64), 0, stream>>>(wP, mix_w, decay, wCarry);
  scan_apply<<<dim3(512), dim3(64), 0, stream>>>(wP, mix_w, mix_b, decay, wCarry, wMix);

  // G2: same shape as G1
  gemm256q<1><<<dim3(4, 64), dim3(512), 0, stream>>>(
      wMix, wWo, out_b, x, (void*)out, MROWS, 1024, 1024,
      4, 1, 8);

  ln_to_bf16<<<dim3(MROWS), dim3(256), 0, stream>>>(out, ln2_g, ln2_b, wMix);

  // G3: px=4, gxp=4, byper=32
  gemm256q<2><<<dim3(16, 64), dim3(512), 0, stream>>>(
      wMix, wW1, ff_b1, (const float*)nullptr, (void*)wU, MROWS, 4096, 1024,
      4, 4, 32);

  // G4: px=2, gxp=2, byper=16
  gemm256q<1><<<dim3(4, 64), dim3(512), 0, stream>>>(
      wU, wW2, ff_b2, out, (void*)out, MROWS, 1024, 4096,
      2, 2, 16);
}